// Round 2
// baseline (1288.217 us; speedup 1.0000x reference)
//
#include <hip/hip_runtime.h>
#include <hip/hip_bf16.h>

typedef unsigned short u16;
typedef __bf16 bf16_t;
typedef bf16_t bf16x8 __attribute__((ext_vector_type(8)));
typedef float f32x4 __attribute__((ext_vector_type(4)));

#define T_TOK 4096
#define DIM   1024
#define NEXP  8
#define HID   2816

static __device__ __forceinline__ u16 f2b(float f) {
    __hip_bfloat16 h = __float2bfloat16(f);
    return *(u16*)&h;
}

// ---------------- gating: fp32 logits -> top2 -> scatter (token,weight) ----------
__global__ void k_gating(const float* __restrict__ X,
                         const float* __restrict__ WG,
                         int* __restrict__ cnt,
                         int* __restrict__ tok,
                         float* __restrict__ wt)
{
    int wv   = threadIdx.x >> 6;
    int lane = threadIdx.x & 63;
    int t = blockIdx.x * 4 + wv;
    float l[NEXP];
#pragma unroll
    for (int e = 0; e < NEXP; ++e) l[e] = 0.f;
#pragma unroll
    for (int i = 0; i < DIM/64; ++i) {
        int d = i*64 + lane;
        float xv = X[(size_t)t*DIM + d];
        const float* wrow = WG + (size_t)d*NEXP;
        float4 wa = *(const float4*)wrow;
        float4 wb = *(const float4*)(wrow + 4);
        l[0] += xv*wa.x; l[1] += xv*wa.y; l[2] += xv*wa.z; l[3] += xv*wa.w;
        l[4] += xv*wb.x; l[5] += xv*wb.y; l[6] += xv*wb.z; l[7] += xv*wb.w;
    }
#pragma unroll
    for (int e = 0; e < NEXP; ++e) {
#pragma unroll
        for (int s = 32; s > 0; s >>= 1)
            l[e] += __shfl_xor(l[e], s, 64);
    }
    if (lane == 0) {
        int i1 = 0; float b1 = l[0];
#pragma unroll
        for (int e = 1; e < NEXP; ++e) if (l[e] > b1) { b1 = l[e]; i1 = e; }
        int i2 = -1; float b2 = 0.f;
#pragma unroll
        for (int e = 0; e < NEXP; ++e) {
            if (e == i1) continue;
            if (i2 < 0 || l[e] > b2) { b2 = l[e]; i2 = e; }
        }
        // 2-way softmax == renormalized top-2 of full softmax
        float p1 = 1.f / (1.f + __expf(b2 - b1));
        float p2 = 1.f - p1;
        int pos = atomicAdd(&cnt[i1], 1);
        tok[i1*T_TOK + pos] = t;  wt[i1*T_TOK + pos] = p1;
        pos = atomicAdd(&cnt[i2], 1);
        tok[i2*T_TOK + pos] = t;  wt[i2*T_TOK + pos] = p2;
    }
}

// ---------------- compact CAP-spaced bins -> expert-contiguous slots -------------
__global__ void k_compact(const int* __restrict__ cnt,
                          const int* __restrict__ tok, const float* __restrict__ wt,
                          int* __restrict__ ctok, float* __restrict__ cwt)
{
    int e = blockIdx.x;
    int off = 0;
    for (int i = 0; i < e; ++i) off += cnt[i];
    int n = cnt[e];
    for (int i = threadIdx.x; i < n; i += blockDim.x) {
        ctok[off + i] = tok[e*T_TOK + i];
        cwt [off + i] = wt [e*T_TOK + i];
    }
}

// ---------------- fused fp32->bf16 cast + 64x64 transpose (per expert z) ---------
// in fp32 [R][C] -> out bf16 [C][R]. LDS stride 72 u16: transposed reads are
// 2-way bank pattern (free); writes 4-way (acceptable, one-time kernel).
__global__ void k_transpose_cast(const float* __restrict__ in, u16* __restrict__ out,
                                 int R, int C)
{
    __shared__ u16 tle[64*72];
    size_t mb = (size_t)blockIdx.z * R * C;
    int r0 = blockIdx.x * 64, c0 = blockIdx.y * 64;
    int tid = threadIdx.x;
    for (int q = tid; q < 1024; q += 256) {
        int r = q >> 4, cc = (q & 15) * 4;
        float4 v = *(const float4*)&in[mb + (size_t)(r0+r)*C + c0 + cc];
        u16 b4[4] = { f2b(v.x), f2b(v.y), f2b(v.z), f2b(v.w) };
        *(uint2*)&tle[r*72 + cc] = *(const uint2*)b4;   // 8B store, aligned
    }
    __syncthreads();
    int hr = tid & 63;
    int dch = tid >> 6;
#pragma unroll
    for (int p = 0; p < 2; ++p) {
        int dc = dch + p*4;
        u16 v[8];
#pragma unroll
        for (int j = 0; j < 8; ++j) v[j] = tle[(dc*8 + j)*72 + hr];
        *(uint4*)&out[mb + (size_t)(c0+hr)*R + r0 + dc*8] = *(const uint4*)v;
    }
}

// ---------------- fp32 X -> bf16 Xbf ---------------------------------------------
__global__ void k_castx(const float* __restrict__ in, u16* __restrict__ out)
{
    size_t i = ((size_t)blockIdx.x * 256 + threadIdx.x) * 8;
    float4 a = *(const float4*)&in[i];
    float4 b = *(const float4*)&in[i + 4];
    u16 v[8] = { f2b(a.x), f2b(a.y), f2b(a.z), f2b(a.w),
                 f2b(b.x), f2b(b.y), f2b(b.z), f2b(b.w) };
    *(uint4*)&out[i] = *(const uint4*)v;
}

// ---------------- GEMM1: H = silu(Xg @ W1) * (Xg @ W3), gathered rows ------------
__global__ __launch_bounds__(256) void k_gemm1(
    const u16* __restrict__ X, const u16* __restrict__ W1t, const u16* __restrict__ W3t,
    u16* __restrict__ Hbuf, const int* __restrict__ cnt, const int* __restrict__ ctok)
{
    __shared__ u16 As [128*40];   // stride 40 u16 (80B): 2-way-free reads/writes
    __shared__ u16 Bs1[64*40];
    __shared__ u16 Bs3[64*40];
    __shared__ int tokLds[128];

    int e  = blockIdx.x >> 5;
    int mt = blockIdx.x & 31;
    int h0 = blockIdx.y * 64;

    int off = 0;
    for (int i = 0; i < e; ++i) off += cnt[i];
    int ne = cnt[e];
    int m0 = mt * 128;
    if (m0 >= ne) return;
    int nvalid = ne - m0; if (nvalid > 128) nvalid = 128;

    int tid = threadIdx.x;
    if (tid < 128) {
        int i = (tid < nvalid) ? tid : 0;
        tokLds[tid] = ctok[off + m0 + i];
    }
    __syncthreads();

    const size_t wbase = (size_t)e * HID * DIM;
    const int wave = tid >> 6, lane = tid & 63, quad = lane >> 4, lr = lane & 15;

    f32x4 acc1[2][4], acc3[2][4];
#pragma unroll
    for (int a = 0; a < 2; ++a)
#pragma unroll
        for (int b = 0; b < 4; ++b) {
            acc1[a][b] = (f32x4){0.f,0.f,0.f,0.f};
            acc3[a][b] = (f32x4){0.f,0.f,0.f,0.f};
        }

    int ar0 = tid >> 2, ac = (tid & 3) * 8;
    int ar1 = ar0 + 64;
    int bn  = tid >> 2, bc = (tid & 3) * 8;

    const u16* xr0 = X + (size_t)tokLds[ar0]*DIM + ac;
    const u16* xr1 = X + (size_t)tokLds[ar1]*DIM + ac;
    const u16* w1p = W1t + wbase + (size_t)(h0 + bn)*DIM + bc;
    const u16* w3p = W3t + wbase + (size_t)(h0 + bn)*DIM + bc;
    u16* asw0 = &As [ar0*40 + ac];
    u16* asw1 = &As [ar1*40 + ac];
    u16* bsw1 = &Bs1[bn*40 + bc];
    u16* bsw3 = &Bs3[bn*40 + bc];

    for (int k0 = 0; k0 < DIM; k0 += 32) {
        __syncthreads();
        *(uint4*)asw0 = *(const uint4*)(xr0 + k0);
        *(uint4*)asw1 = *(const uint4*)(xr1 + k0);
        *(uint4*)bsw1 = *(const uint4*)(w1p + k0);
        *(uint4*)bsw3 = *(const uint4*)(w3p + k0);
        __syncthreads();
        bf16x8 af[2], bf1[4], bf3[4];
#pragma unroll
        for (int m = 0; m < 2; ++m)
            af[m] = *(const bf16x8*)&As[(wave*32 + m*16 + lr)*40 + quad*8];
#pragma unroll
        for (int n = 0; n < 4; ++n) {
            bf1[n] = *(const bf16x8*)&Bs1[(n*16 + lr)*40 + quad*8];
            bf3[n] = *(const bf16x8*)&Bs3[(n*16 + lr)*40 + quad*8];
        }
#pragma unroll
        for (int m = 0; m < 2; ++m)
#pragma unroll
            for (int n = 0; n < 4; ++n) {
                acc1[m][n] = __builtin_amdgcn_mfma_f32_16x16x32_bf16(af[m], bf1[n], acc1[m][n], 0, 0, 0);
                acc3[m][n] = __builtin_amdgcn_mfma_f32_16x16x32_bf16(af[m], bf3[n], acc3[m][n], 0, 0, 0);
            }
    }

    // C/D layout: row = quad*4 + r, col = lr  (m89/m91-verified)
#pragma unroll
    for (int m = 0; m < 2; ++m) {
        int mb = wave*32 + m*16 + quad*4;
#pragma unroll
        for (int r = 0; r < 4; ++r) {
            int mm = mb + r;
            if (mm >= nvalid) continue;
            u16* hrow = Hbuf + (size_t)(off + m0 + mm)*HID + h0 + lr;
#pragma unroll
            for (int n = 0; n < 4; ++n) {
                float g = acc1[m][n][r];
                float u = acc3[m][n][r];
                float hv = (g / (1.f + __expf(-g))) * u;   // silu(g)*u
                hrow[n*16] = f2b(hv);
            }
        }
    }
}

// ---------------- GEMM2: d_out[t] += w_slot * (H @ W2) ---------------------------
__global__ __launch_bounds__(256) void k_gemm2(
    const u16* __restrict__ Hbuf, const u16* __restrict__ W2t,
    float* __restrict__ outf, const int* __restrict__ cnt,
    const int* __restrict__ ctok, const float* __restrict__ cwt)
{
    __shared__ u16 As[128*40];
    __shared__ u16 Bs[64*40];
    __shared__ int   tLds[128];
    __shared__ float wLds[128];

    int e  = blockIdx.x >> 5;
    int mt = blockIdx.x & 31;
    int d0 = blockIdx.y * 64;

    int off = 0;
    for (int i = 0; i < e; ++i) off += cnt[i];
    int ne = cnt[e];
    int m0 = mt * 128;
    if (m0 >= ne) return;
    int nvalid = ne - m0; if (nvalid > 128) nvalid = 128;

    int tid = threadIdx.x;
    if (tid < 128) {
        int i = (tid < nvalid) ? tid : 0;
        tLds[tid] = ctok[off + m0 + i];
        wLds[tid] = cwt [off + m0 + i];
    }

    const int wave = tid >> 6, lane = tid & 63, quad = lane >> 4, lr = lane & 15;

    f32x4 acc[2][4];
#pragma unroll
    for (int a = 0; a < 2; ++a)
#pragma unroll
        for (int b = 0; b < 4; ++b) acc[a][b] = (f32x4){0.f,0.f,0.f,0.f};

    int ar0 = tid >> 2, ac = (tid & 3) * 8;
    int ar1 = ar0 + 64;
    int bn  = tid >> 2, bc = (tid & 3) * 8;
    int car0 = (ar0 < nvalid) ? ar0 : 0;
    int car1 = (ar1 < nvalid) ? ar1 : 0;

    const u16* h0p = Hbuf + (size_t)(off + m0 + car0)*HID + ac;
    const u16* h1p = Hbuf + (size_t)(off + m0 + car1)*HID + ac;
    const u16* w2p = W2t + (size_t)e*DIM*HID + (size_t)(d0 + bn)*HID + bc;
    u16* asw0 = &As[ar0*40 + ac];
    u16* asw1 = &As[ar1*40 + ac];
    u16* bsw  = &Bs[bn*40 + bc];

    for (int k0 = 0; k0 < HID; k0 += 32) {
        __syncthreads();
        *(uint4*)asw0 = *(const uint4*)(h0p + k0);
        *(uint4*)asw1 = *(const uint4*)(h1p + k0);
        *(uint4*)bsw  = *(const uint4*)(w2p + k0);
        __syncthreads();
        bf16x8 af[2], bfr[4];
#pragma unroll
        for (int m = 0; m < 2; ++m)
            af[m] = *(const bf16x8*)&As[(wave*32 + m*16 + lr)*40 + quad*8];
#pragma unroll
        for (int n = 0; n < 4; ++n)
            bfr[n] = *(const bf16x8*)&Bs[(n*16 + lr)*40 + quad*8];
#pragma unroll
        for (int m = 0; m < 2; ++m)
#pragma unroll
            for (int n = 0; n < 4; ++n)
                acc[m][n] = __builtin_amdgcn_mfma_f32_16x16x32_bf16(af[m], bfr[n], acc[m][n], 0, 0, 0);
    }

#pragma unroll
    for (int m = 0; m < 2; ++m) {
        int mb = wave*32 + m*16 + quad*4;
#pragma unroll
        for (int r = 0; r < 4; ++r) {
            int mm = mb + r;
            if (mm >= nvalid) continue;
            float wr = wLds[mm];
            float* orow = outf + (size_t)tLds[mm]*DIM + d0 + lr;
#pragma unroll
            for (int n = 0; n < 4; ++n)
                atomicAdd(&orow[n*16], acc[m][n][r] * wr);
        }
    }
}

extern "C" void kernel_launch(void* const* d_in, const int* in_sizes, int n_in,
                              void* d_out, int out_size, void* d_ws, size_t ws_size,
                              hipStream_t stream)
{
    const float* x  = (const float*)d_in[0];
    const float* wg = (const float*)d_in[1];
    const float* w1 = (const float*)d_in[2];
    const float* w2 = (const float*)d_in[3];
    const float* w3 = (const float*)d_in[4];
    float* outf = (float*)d_out;

    char* ws = (char*)d_ws;
    int*   cnt  = (int*)  (ws);                       //        256 B
    int*   tok  = (int*)  (ws + 256);                 //    131,072
    float* wt   = (float*)(ws + 131328);              //    131,072
    int*   ctok = (int*)  (ws + 262400);              //     32,768
    float* cwt  = (float*)(ws + 295168);              //     32,768
    u16*   Xbf  = (u16*)  (ws + 327936);              //  8,388,608
    u16*   Hbuf = (u16*)  (ws + 8716544);             // 46,137,344
    u16*   W1t  = (u16*)  (ws + 54853888);            // 46,137,344
    u16*   W3t  = (u16*)  (ws + 100991232);           // 46,137,344
    u16*   W2t  = (u16*)  (ws + 147128576);           // 46,137,344 -> 193,265,920 total

    hipMemsetAsync(cnt, 0, 256, stream);
    hipMemsetAsync(outf, 0, (size_t)T_TOK*DIM*sizeof(float), stream);

    // W1,W3: fp32 [D][H] per expert -> bf16 [H][D] ; W2: fp32 [H][D] -> bf16 [D][H]
    k_transpose_cast<<<dim3(DIM/64, HID/64, NEXP), 256, 0, stream>>>(w1, W1t, DIM, HID);
    k_transpose_cast<<<dim3(DIM/64, HID/64, NEXP), 256, 0, stream>>>(w3, W3t, DIM, HID);
    k_transpose_cast<<<dim3(HID/64, DIM/64, NEXP), 256, 0, stream>>>(w2, W2t, HID, DIM);
    k_castx<<<(T_TOK*DIM/8)/256, 256, 0, stream>>>(x, Xbf);

    k_gating<<<T_TOK/4, 256, 0, stream>>>(x, wg, cnt, tok, wt);
    k_compact<<<NEXP, 256, 0, stream>>>(cnt, tok, wt, ctok, cwt);

    k_gemm1<<<dim3(NEXP*32, HID/64), 256, 0, stream>>>(Xbf, W1t, W3t, Hbuf, cnt, ctok);
    k_gemm2<<<dim3(NEXP*32, DIM/64), 256, 0, stream>>>(Hbuf, W2t, outf, cnt, ctok, cwt);
}

// Round 3
// 740.063 us; speedup vs baseline: 1.7407x; 1.7407x over previous
//
#include <hip/hip_runtime.h>
#include <hip/hip_bf16.h>

typedef unsigned short u16;
typedef __bf16 bf16_t;
typedef bf16_t bf16x8 __attribute__((ext_vector_type(8)));
typedef float f32x4 __attribute__((ext_vector_type(4)));

#define T_TOK 4096
#define DIM   1024
#define NEXP  8
#define HID   2816

static __device__ __forceinline__ u16 f2b(float f) {
    __hip_bfloat16 h = __float2bfloat16(f);
    return *(u16*)&h;
}

// async global->LDS, 16B per lane; LDS dest = wave-uniform base + lane*16
static __device__ __forceinline__ void glds16(const u16* g, u16* l) {
    __builtin_amdgcn_global_load_lds((const __attribute__((address_space(1))) void*)g,
                                     (__attribute__((address_space(3))) void*)l, 16, 0, 0);
}

// ---------------- gating: fp32 logits -> top2 -> scatter (token,weight) ----------
__global__ void k_gating(const float* __restrict__ X,
                         const float* __restrict__ WG,
                         int* __restrict__ cnt,
                         int* __restrict__ tok,
                         float* __restrict__ wt)
{
    int wv   = threadIdx.x >> 6;
    int lane = threadIdx.x & 63;
    int t = blockIdx.x * 4 + wv;
    float l[NEXP];
#pragma unroll
    for (int e = 0; e < NEXP; ++e) l[e] = 0.f;
#pragma unroll
    for (int i = 0; i < DIM/64; ++i) {
        int d = i*64 + lane;
        float xv = X[(size_t)t*DIM + d];
        const float* wrow = WG + (size_t)d*NEXP;
        float4 wa = *(const float4*)wrow;
        float4 wb = *(const float4*)(wrow + 4);
        l[0] += xv*wa.x; l[1] += xv*wa.y; l[2] += xv*wa.z; l[3] += xv*wa.w;
        l[4] += xv*wb.x; l[5] += xv*wb.y; l[6] += xv*wb.z; l[7] += xv*wb.w;
    }
#pragma unroll
    for (int e = 0; e < NEXP; ++e) {
#pragma unroll
        for (int s = 32; s > 0; s >>= 1)
            l[e] += __shfl_xor(l[e], s, 64);
    }
    if (lane == 0) {
        int i1 = 0; float b1 = l[0];
#pragma unroll
        for (int e = 1; e < NEXP; ++e) if (l[e] > b1) { b1 = l[e]; i1 = e; }
        int i2 = -1; float b2 = 0.f;
#pragma unroll
        for (int e = 0; e < NEXP; ++e) {
            if (e == i1) continue;
            if (i2 < 0 || l[e] > b2) { b2 = l[e]; i2 = e; }
        }
        float p1 = 1.f / (1.f + __expf(b2 - b1));
        float p2 = 1.f - p1;
        int pos = atomicAdd(&cnt[i1], 1);
        tok[i1*T_TOK + pos] = t;  wt[i1*T_TOK + pos] = p1;
        pos = atomicAdd(&cnt[i2], 1);
        tok[i2*T_TOK + pos] = t;  wt[i2*T_TOK + pos] = p2;
    }
}

// ---------------- compact CAP-spaced bins -> expert-contiguous slots -------------
__global__ void k_compact(const int* __restrict__ cnt,
                          const int* __restrict__ tok, const float* __restrict__ wt,
                          int* __restrict__ ctok, float* __restrict__ cwt)
{
    int e = blockIdx.x;
    int off = 0;
    for (int i = 0; i < e; ++i) off += cnt[i];
    int n = cnt[e];
    for (int i = threadIdx.x; i < n; i += blockDim.x) {
        ctok[off + i] = tok[e*T_TOK + i];
        cwt [off + i] = wt [e*T_TOK + i];
    }
}

// ---------------- fused fp32->bf16 cast + 64x64 transpose (per expert z) ---------
__global__ void k_transpose_cast(const float* __restrict__ in, u16* __restrict__ out,
                                 int R, int C)
{
    __shared__ u16 tle[64*72];
    size_t mb = (size_t)blockIdx.z * R * C;
    int r0 = blockIdx.x * 64, c0 = blockIdx.y * 64;
    int tid = threadIdx.x;
    for (int q = tid; q < 1024; q += 256) {
        int r = q >> 4, cc = (q & 15) * 4;
        float4 v = *(const float4*)&in[mb + (size_t)(r0+r)*C + c0 + cc];
        u16 b4[4] = { f2b(v.x), f2b(v.y), f2b(v.z), f2b(v.w) };
        *(uint2*)&tle[r*72 + cc] = *(const uint2*)b4;
    }
    __syncthreads();
    int hr = tid & 63;
    int dch = tid >> 6;
#pragma unroll
    for (int p = 0; p < 2; ++p) {
        int dc = dch + p*4;
        u16 v[8];
#pragma unroll
        for (int j = 0; j < 8; ++j) v[j] = tle[(dc*8 + j)*72 + hr];
        *(uint4*)&out[mb + (size_t)(c0+hr)*R + r0 + dc*8] = *(const uint4*)v;
    }
}

// ---------------- fp32 X -> bf16 Xbf ---------------------------------------------
__global__ void k_castx(const float* __restrict__ in, u16* __restrict__ out)
{
    size_t i = ((size_t)blockIdx.x * 256 + threadIdx.x) * 8;
    float4 a = *(const float4*)&in[i];
    float4 b = *(const float4*)&in[i + 4];
    u16 v[8] = { f2b(a.x), f2b(a.y), f2b(a.z), f2b(a.w),
                 f2b(b.x), f2b(b.y), f2b(b.z), f2b(b.w) };
    *(uint4*)&out[i] = *(const uint4*)v;
}

// ---------------- GEMM1: H = silu(Xg@W1) * (Xg@W3); mt-loop inside block ---------
// grid (HID/64, NEXP, 2). Tile 128 tok x (64 W1 | 64 W3), BK=32, async staging.
__global__ __launch_bounds__(256) void k_gemm1(
    const u16* __restrict__ X, const u16* __restrict__ W1t, const u16* __restrict__ W3t,
    u16* __restrict__ Hbuf, const int* __restrict__ cnt, const int* __restrict__ ctok)
{
    __shared__ u16 As[128*32];      // unpadded: global_load_lds layout; b128 reads at 8-cyc floor
    __shared__ u16 Bs[128*32];      // rows 0-63 = W1 cols, rows 64-127 = W3 cols
    __shared__ int tokLds[128];

    const int h0 = blockIdx.x * 64;
    const int e  = blockIdx.y;
    const int z  = blockIdx.z;

    int off = 0;
    for (int i = 0; i < e; ++i) off += cnt[i];
    const int ne = cnt[e];
    const int ntile = (ne + 127) >> 7;

    const int tid = threadIdx.x, wave = tid >> 6, lane = tid & 63;
    const int quad = lane >> 4, lr = lane & 15;
    const int lrow = lane >> 2;              // 0..15 row within 1KB chunk
    const int koff = (lane & 3) * 8;         // elem offset in row: 0,8,16,24

    const size_t wbase = (size_t)e * HID * DIM;
    const u16* Wsel = (wave < 2) ? W1t : W3t;
    const int bcol0 = ((wave * 32) & 63) + lrow;
    const u16* bg0 = Wsel + wbase + (size_t)(h0 + bcol0)      * DIM + koff;
    const u16* bg1 = Wsel + wbase + (size_t)(h0 + bcol0 + 16) * DIM + koff;
    u16* al0 = &As[(wave*32)      * 32];
    u16* al1 = &As[(wave*32 + 16) * 32];
    u16* bl0 = &Bs[(wave*32)      * 32];
    u16* bl1 = &Bs[(wave*32 + 16) * 32];

    for (int mt = z; mt < ntile; mt += 2) {
        const int m0 = mt << 7;
        int nvalid = ne - m0; if (nvalid > 128) nvalid = 128;

        __syncthreads();                       // prior sweep fully done with LDS
        if (tid < 128) {
            int i = (tid < nvalid) ? tid : (nvalid - 1);
            tokLds[tid] = ctok[off + m0 + i];
        }
        __syncthreads();
        const u16* ag0 = X + (size_t)tokLds[wave*32 + lrow]      * DIM + koff;
        const u16* ag1 = X + (size_t)tokLds[wave*32 + 16 + lrow] * DIM + koff;

        f32x4 acc1[2][4], acc3[2][4];
#pragma unroll
        for (int a = 0; a < 2; ++a)
#pragma unroll
            for (int b = 0; b < 4; ++b) {
                acc1[a][b] = (f32x4){0.f,0.f,0.f,0.f};
                acc3[a][b] = (f32x4){0.f,0.f,0.f,0.f};
            }

        for (int k0 = 0; k0 < DIM; k0 += 32) {
            __syncthreads();                   // readers of previous slab done
            glds16(ag0 + k0, al0);
            glds16(ag1 + k0, al1);
            glds16(bg0 + k0, bl0);
            glds16(bg1 + k0, bl1);
            __syncthreads();                   // vmcnt(0) drain makes slab visible
            bf16x8 af[2], b1[4], b3[4];
#pragma unroll
            for (int m = 0; m < 2; ++m)
                af[m] = *(const bf16x8*)&As[(wave*32 + m*16 + lr)*32 + quad*8];
#pragma unroll
            for (int n = 0; n < 4; ++n) {
                b1[n] = *(const bf16x8*)&Bs[(n*16 + lr)*32 + quad*8];
                b3[n] = *(const bf16x8*)&Bs[(64 + n*16 + lr)*32 + quad*8];
            }
#pragma unroll
            for (int m = 0; m < 2; ++m)
#pragma unroll
                for (int n = 0; n < 4; ++n) {
                    acc1[m][n] = __builtin_amdgcn_mfma_f32_16x16x32_bf16(af[m], b1[n], acc1[m][n], 0, 0, 0);
                    acc3[m][n] = __builtin_amdgcn_mfma_f32_16x16x32_bf16(af[m], b3[n], acc3[m][n], 0, 0, 0);
                }
        }

        // C/D: row = quad*4 + r, col = lr
#pragma unroll
        for (int m = 0; m < 2; ++m) {
            int mb = wave*32 + m*16 + quad*4;
#pragma unroll
            for (int r = 0; r < 4; ++r) {
                int mm = mb + r;
                if (mm >= nvalid) continue;
                u16* hrow = Hbuf + (size_t)(off + m0 + mm)*HID + h0 + lr;
#pragma unroll
                for (int n = 0; n < 4; ++n) {
                    float g = acc1[m][n][r];
                    float u = acc3[m][n][r];
                    hrow[n*16] = f2b((g / (1.f + __expf(-g))) * u);
                }
            }
        }
    }
}

// ---------------- GEMM2: out[t] += w * (H@W2); mt-loop inside, K-split x4 --------
// grid (DIM/128, NEXP, 8): z = zmt*4 + zk. Tile 128 tok x 128 d-cols, BK=32.
__global__ __launch_bounds__(256) void k_gemm2(
    const u16* __restrict__ Hbuf, const u16* __restrict__ W2t,
    float* __restrict__ outf, const int* __restrict__ cnt,
    const int* __restrict__ ctok, const float* __restrict__ cwt)
{
    __shared__ u16 As[128*32];
    __shared__ u16 Bs[128*32];
    __shared__ int   tLds[128];
    __shared__ float wLds[128];

    const int d0  = blockIdx.x * 128;
    const int e   = blockIdx.y;
    const int zmt = blockIdx.z >> 2;
    const int zk  = blockIdx.z & 3;
    const int kbase = zk * (HID/4);          // 704-elem K slice
    const int kend  = kbase + (HID/4);

    int off = 0;
    for (int i = 0; i < e; ++i) off += cnt[i];
    const int ne = cnt[e];
    const int ntile = (ne + 127) >> 7;

    const int tid = threadIdx.x, wave = tid >> 6, lane = tid & 63;
    const int quad = lane >> 4, lr = lane & 15;
    const int lrow = lane >> 2;
    const int koff = (lane & 3) * 8;

    const size_t w2base = (size_t)e * DIM * HID;
    const int bcol = wave*32 + lrow;
    const u16* bg0 = W2t + w2base + (size_t)(d0 + bcol)      * HID + koff;
    const u16* bg1 = W2t + w2base + (size_t)(d0 + bcol + 16) * HID + koff;
    u16* al0 = &As[(wave*32)      * 32];
    u16* al1 = &As[(wave*32 + 16) * 32];
    u16* bl0 = &Bs[(wave*32)      * 32];
    u16* bl1 = &Bs[(wave*32 + 16) * 32];

    for (int mt = zmt; mt < ntile; mt += 2) {
        const int m0 = mt << 7;
        int nvalid = ne - m0; if (nvalid > 128) nvalid = 128;

        __syncthreads();
        if (tid < 128) {
            int i = (tid < nvalid) ? tid : (nvalid - 1);
            tLds[tid] = ctok[off + m0 + i];
            wLds[tid] = cwt [off + m0 + i];
        }
        __syncthreads();
        int ar0 = wave*32 + lrow;       int ar0c = (ar0 < nvalid) ? ar0 : (nvalid - 1);
        int ar1 = ar0 + 16;             int ar1c = (ar1 < nvalid) ? ar1 : (nvalid - 1);
        const u16* ag0 = Hbuf + (size_t)(off + m0 + ar0c)*HID + koff;
        const u16* ag1 = Hbuf + (size_t)(off + m0 + ar1c)*HID + koff;

        f32x4 acc[2][8];
#pragma unroll
        for (int a = 0; a < 2; ++a)
#pragma unroll
            for (int b = 0; b < 8; ++b) acc[a][b] = (f32x4){0.f,0.f,0.f,0.f};

        for (int k0 = kbase; k0 < kend; k0 += 32) {
            __syncthreads();
            glds16(ag0 + k0, al0);
            glds16(ag1 + k0, al1);
            glds16(bg0 + k0, bl0);
            glds16(bg1 + k0, bl1);
            __syncthreads();
            bf16x8 af[2], bfr[8];
#pragma unroll
            for (int m = 0; m < 2; ++m)
                af[m] = *(const bf16x8*)&As[(wave*32 + m*16 + lr)*32 + quad*8];
#pragma unroll
            for (int n = 0; n < 8; ++n)
                bfr[n] = *(const bf16x8*)&Bs[(n*16 + lr)*32 + quad*8];
#pragma unroll
            for (int m = 0; m < 2; ++m)
#pragma unroll
                for (int n = 0; n < 8; ++n)
                    acc[m][n] = __builtin_amdgcn_mfma_f32_16x16x32_bf16(af[m], bfr[n], acc[m][n], 0, 0, 0);
        }

#pragma unroll
        for (int m = 0; m < 2; ++m) {
            int mb = wave*32 + m*16 + quad*4;
#pragma unroll
            for (int r = 0; r < 4; ++r) {
                int mm = mb + r;
                if (mm >= nvalid) continue;
                float wr = wLds[mm];
                float* orow = outf + (size_t)tLds[mm]*DIM + d0 + lr;
#pragma unroll
                for (int n = 0; n < 8; ++n)
                    atomicAdd(&orow[n*16], acc[m][n][r] * wr);
            }
        }
    }
}

extern "C" void kernel_launch(void* const* d_in, const int* in_sizes, int n_in,
                              void* d_out, int out_size, void* d_ws, size_t ws_size,
                              hipStream_t stream)
{
    const float* x  = (const float*)d_in[0];
    const float* wg = (const float*)d_in[1];
    const float* w1 = (const float*)d_in[2];
    const float* w2 = (const float*)d_in[3];
    const float* w3 = (const float*)d_in[4];
    float* outf = (float*)d_out;

    char* ws = (char*)d_ws;
    int*   cnt  = (int*)  (ws);                       //        256 B
    int*   tok  = (int*)  (ws + 256);                 //    131,072
    float* wt   = (float*)(ws + 131328);              //    131,072
    int*   ctok = (int*)  (ws + 262400);              //     32,768
    float* cwt  = (float*)(ws + 295168);              //     32,768
    u16*   Xbf  = (u16*)  (ws + 327936);              //  8,388,608
    u16*   Hbuf = (u16*)  (ws + 8716544);             // 46,137,344
    u16*   W1t  = (u16*)  (ws + 54853888);            // 46,137,344
    u16*   W3t  = (u16*)  (ws + 100991232);           // 46,137,344
    u16*   W2t  = (u16*)  (ws + 147128576);           // 46,137,344 -> 193,265,920 total

    hipMemsetAsync(cnt, 0, 256, stream);
    hipMemsetAsync(outf, 0, (size_t)T_TOK*DIM*sizeof(float), stream);

    k_transpose_cast<<<dim3(DIM/64, HID/64, NEXP), 256, 0, stream>>>(w1, W1t, DIM, HID);
    k_transpose_cast<<<dim3(DIM/64, HID/64, NEXP), 256, 0, stream>>>(w3, W3t, DIM, HID);
    k_transpose_cast<<<dim3(HID/64, DIM/64, NEXP), 256, 0, stream>>>(w2, W2t, HID, DIM);
    k_castx<<<(T_TOK*DIM/8)/256, 256, 0, stream>>>(x, Xbf);

    k_gating<<<T_TOK/4, 256, 0, stream>>>(x, wg, cnt, tok, wt);
    k_compact<<<NEXP, 256, 0, stream>>>(cnt, tok, wt, ctok, cwt);

    k_gemm1<<<dim3(HID/64, NEXP, 2), 256, 0, stream>>>(Xbf, W1t, W3t, Hbuf, cnt, ctok);
    k_gemm2<<<dim3(DIM/128, NEXP, 8), 256, 0, stream>>>(Hbuf, W2t, outf, cnt, ctok, cwt);
}

// Round 4
// 671.606 us; speedup vs baseline: 1.9181x; 1.1019x over previous
//
#include <hip/hip_runtime.h>
#include <hip/hip_bf16.h>

typedef unsigned short u16;
typedef __bf16 bf16_t;
typedef bf16_t bf16x8 __attribute__((ext_vector_type(8)));
typedef float f32x4 __attribute__((ext_vector_type(4)));

#define T_TOK 4096
#define DIM   1024
#define NEXP  8
#define HID   2816
#define CAP   16

static __device__ __forceinline__ u16 f2b(float f) {
    __hip_bfloat16 h = __float2bfloat16(f);
    return *(u16*)&h;
}

// async global->LDS: HW writes lane i's 16B at (wave-uniform base)+i*16
static __device__ __forceinline__ void glds16(const u16* g, u16* l) {
    __builtin_amdgcn_global_load_lds((const __attribute__((address_space(1))) void*)g,
                                     (__attribute__((address_space(3))) void*)l, 16, 0, 0);
}

// ---------------- gating (+ fused fp32->bf16 X cast) -----------------------------
__global__ void k_gating(const float* __restrict__ X,
                         const float* __restrict__ WG,
                         int* __restrict__ cnt,
                         int* __restrict__ tok,
                         float* __restrict__ wt,
                         u16* __restrict__ Xbf)
{
    int wv   = threadIdx.x >> 6;
    int lane = threadIdx.x & 63;
    int t = blockIdx.x * 4 + wv;
    float l[NEXP];
#pragma unroll
    for (int e = 0; e < NEXP; ++e) l[e] = 0.f;
#pragma unroll
    for (int i = 0; i < DIM/64; ++i) {
        int d = i*64 + lane;
        float xv = X[(size_t)t*DIM + d];
        Xbf[(size_t)t*DIM + d] = f2b(xv);
        const float* wrow = WG + (size_t)d*NEXP;
        float4 wa = *(const float4*)wrow;
        float4 wb = *(const float4*)(wrow + 4);
        l[0] += xv*wa.x; l[1] += xv*wa.y; l[2] += xv*wa.z; l[3] += xv*wa.w;
        l[4] += xv*wb.x; l[5] += xv*wb.y; l[6] += xv*wb.z; l[7] += xv*wb.w;
    }
#pragma unroll
    for (int e = 0; e < NEXP; ++e) {
#pragma unroll
        for (int s = 32; s > 0; s >>= 1)
            l[e] += __shfl_xor(l[e], s, 64);
    }
    if (lane == 0) {
        int i1 = 0; float b1 = l[0];
#pragma unroll
        for (int e = 1; e < NEXP; ++e) if (l[e] > b1) { b1 = l[e]; i1 = e; }
        int i2 = -1; float b2 = 0.f;
#pragma unroll
        for (int e = 0; e < NEXP; ++e) {
            if (e == i1) continue;
            if (i2 < 0 || l[e] > b2) { b2 = l[e]; i2 = e; }
        }
        float p1 = 1.f / (1.f + __expf(b2 - b1));
        float p2 = 1.f - p1;
        int pos = atomicAdd(&cnt[i1], 1);
        tok[i1*T_TOK + pos] = t;  wt[i1*T_TOK + pos] = p1;
        pos = atomicAdd(&cnt[i2], 1);
        tok[i2*T_TOK + pos] = t;  wt[i2*T_TOK + pos] = p2;
    }
}

// ---------------- compact CAP-spaced bins -> expert-contiguous slots -------------
__global__ void k_compact(const int* __restrict__ cnt,
                          const int* __restrict__ tok, const float* __restrict__ wt,
                          int* __restrict__ ctok, float* __restrict__ cwt)
{
    int e = blockIdx.x;
    int off = 0;
    for (int i = 0; i < e; ++i) off += cnt[i];
    int n = cnt[e];
    for (int i = threadIdx.x; i < n; i += blockDim.x) {
        ctok[off + i] = tok[e*T_TOK + i];
        cwt [off + i] = wt [e*T_TOK + i];
    }
}

// ---------------- fused fp32->bf16 cast + 64x64 transpose ------------------------
// LDS held TRANSPOSED ([c][r], stride 72): phase-2 is b128 read + 128B-coalesced
// global stores (8 lanes per output row). Phase-1 scalar LDS writes conflict
// ~8-way but kernel is HBM-bound.
#define TS 72
__global__ void k_transpose_cast(const float* __restrict__ in, u16* __restrict__ out,
                                 int R, int C)
{
    __shared__ u16 tle[64*TS];
    size_t mb = (size_t)blockIdx.z * (size_t)R * C;
    int r0 = blockIdx.x * 64, c0 = blockIdx.y * 64;
    int tid = threadIdx.x;
    const float* I = in + mb + (size_t)r0*C + c0;
#pragma unroll
    for (int p = 0; p < 4; ++p) {
        int q = tid + p*256;
        int r = q >> 4, cc = (q & 15) * 4;
        float4 v = *(const float4*)&I[(size_t)r*C + cc];
        tle[(cc+0)*TS + r] = f2b(v.x);
        tle[(cc+1)*TS + r] = f2b(v.y);
        tle[(cc+2)*TS + r] = f2b(v.z);
        tle[(cc+3)*TS + r] = f2b(v.w);
    }
    __syncthreads();
    u16* O = out + mb + (size_t)c0*R + r0;
    int rc = tid & 7, oc = tid >> 3;
#pragma unroll
    for (int p = 0; p < 2; ++p) {
        int c = oc + p*32;
        *(uint4*)&O[(size_t)c*R + rc*8] = *(const uint4*)&tle[c*TS + rc*8];
    }
}

// ---------------- GEMM1: H = silu(Xg@W1) * (Xg@W3) -------------------------------
// flat grid 8*44*CAP; e = bid&7 (XCD affinity), q=bid>>3: mt fastest, col next.
// Tile 128 tok x 64 h (both W1 and W3), BK=32; 2x2 waves, 16 MFMA/wave/iter.
__global__ __launch_bounds__(256, 3) void k_gemm1(
    const u16* __restrict__ X, const u16* __restrict__ W1t, const u16* __restrict__ W3t,
    u16* __restrict__ Hbuf, const int* __restrict__ cnt, const int* __restrict__ ctok)
{
    __shared__ u16 As[128*32];
    __shared__ u16 Bs[128*32];     // rows 0-63: W1 cols, 64-127: W3 cols
    __shared__ int tokLds[128];

    const int bid = blockIdx.x;
    const int e   = bid & 7;
    const int q   = bid >> 3;
    const int mt0 = q & (CAP-1);
    const int col = q >> 4;                  // 0..43
    const int ne  = cnt[e];
    const int ntile = (ne + 127) >> 7;
    if (mt0 >= ntile) return;
    int off = 0;
    for (int i = 0; i < e; ++i) off += cnt[i];
    const int h0 = col * 64;

    const int tid = threadIdx.x, wave = tid >> 6, lane = tid & 63;
    const int wr = wave >> 1, wc = wave & 1;
    const int quad = lane >> 4, lr = lane & 15;
    const int lrow = lane >> 2, lko = (lane & 3) * 8;

    const size_t wb = (size_t)e * HID * DIM;
    const u16* w1g = W1t + wb + (size_t)(h0 + wave*16 + lrow)*DIM + lko;
    const u16* w3g = W3t + wb + (size_t)(h0 + wave*16 + lrow)*DIM + lko;
    u16* aL0 = &As[(wave*16)*32];
    u16* aL1 = &As[(64 + wave*16)*32];
    u16* bL0 = &Bs[(wave*16)*32];
    u16* bL1 = &Bs[(64 + wave*16)*32];

    for (int tile = mt0; tile < ntile; tile += CAP) {
        const int m0 = tile << 7;
        int nvalid = ne - m0; if (nvalid > 128) nvalid = 128;

        __syncthreads();
        if (tid < 128) {
            int i = (tid < nvalid) ? tid : (nvalid - 1);
            tokLds[tid] = ctok[off + m0 + i];
        }
        __syncthreads();
        const u16* ag0 = X + (size_t)tokLds[wave*16 + lrow]*DIM + lko;
        const u16* ag1 = X + (size_t)tokLds[64 + wave*16 + lrow]*DIM + lko;

        f32x4 a1[4][2], a3[4][2];
#pragma unroll
        for (int m = 0; m < 4; ++m)
#pragma unroll
            for (int n = 0; n < 2; ++n) {
                a1[m][n] = (f32x4){0.f,0.f,0.f,0.f};
                a3[m][n] = (f32x4){0.f,0.f,0.f,0.f};
            }

        for (int k0 = 0; k0 < DIM; k0 += 32) {
            __syncthreads();
            glds16(ag0 + k0, aL0);
            glds16(ag1 + k0, aL1);
            glds16(w1g + k0, bL0);
            glds16(w3g + k0, bL1);
            __syncthreads();
            bf16x8 af[4], b1[2], b3[2];
#pragma unroll
            for (int m = 0; m < 4; ++m)
                af[m] = *(const bf16x8*)&As[(wr*64 + m*16 + lr)*32 + quad*8];
#pragma unroll
            for (int n = 0; n < 2; ++n) {
                b1[n] = *(const bf16x8*)&Bs[(wc*32 + n*16 + lr)*32 + quad*8];
                b3[n] = *(const bf16x8*)&Bs[(64 + wc*32 + n*16 + lr)*32 + quad*8];
            }
#pragma unroll
            for (int m = 0; m < 4; ++m)
#pragma unroll
                for (int n = 0; n < 2; ++n) {
                    a1[m][n] = __builtin_amdgcn_mfma_f32_16x16x32_bf16(af[m], b1[n], a1[m][n], 0, 0, 0);
                    a3[m][n] = __builtin_amdgcn_mfma_f32_16x16x32_bf16(af[m], b3[n], a3[m][n], 0, 0, 0);
                }
        }

        // C/D: row = quad*4 + rr, col = lr
#pragma unroll
        for (int m = 0; m < 4; ++m) {
            int mb_ = wr*64 + m*16 + quad*4;
#pragma unroll
            for (int rr = 0; rr < 4; ++rr) {
                int mm = mb_ + rr;
                if (mm >= nvalid) continue;
                u16* hrow = Hbuf + (size_t)(off + m0 + mm)*HID + h0 + wc*32 + lr;
#pragma unroll
                for (int n = 0; n < 2; ++n) {
                    float g = a1[m][n][rr];
                    float u = a3[m][n][rr];
                    hrow[n*16] = f2b((g / (1.f + __expf(-g))) * u);
                }
            }
        }
    }
}

// ---------------- GEMM2: out[t] += w * (H@W2) ------------------------------------
// flat grid 8*16*2*8; e=bid&7 (XCD affinity); q: mt fastest, then zk, then d0.
// Tile 128 tok x 128 d, K-split 2 (1408), 2x2 waves, 16 MFMA/wave/iter.
__global__ __launch_bounds__(256, 3) void k_gemm2(
    const u16* __restrict__ Hbuf, const u16* __restrict__ W2t,
    float* __restrict__ outf, const int* __restrict__ cnt,
    const int* __restrict__ ctok, const float* __restrict__ cwt)
{
    __shared__ u16 As[128*32];
    __shared__ u16 Bs[128*32];
    __shared__ int   tLds[128];
    __shared__ float wLds[128];

    const int bid = blockIdx.x;
    const int e   = bid & 7;
    const int q   = bid >> 3;
    const int mt0 = q & (CAP-1);
    const int r2  = q >> 4;
    const int zk  = r2 & 1;
    const int d0  = (r2 >> 1) * 128;
    const int ne  = cnt[e];
    const int ntile = (ne + 127) >> 7;
    if (mt0 >= ntile) return;
    int off = 0;
    for (int i = 0; i < e; ++i) off += cnt[i];
    const int kb = zk * (HID/2);             // 1408-elem K slice

    const int tid = threadIdx.x, wave = tid >> 6, lane = tid & 63;
    const int wr = wave >> 1, wc = wave & 1;
    const int quad = lane >> 4, lr = lane & 15;
    const int lrow = lane >> 2, lko = (lane & 3) * 8;

    const size_t w2b = (size_t)e * DIM * HID;
    const u16* bg0 = W2t + w2b + (size_t)(d0 + wave*16 + lrow)*HID + kb + lko;
    const u16* bg1 = bg0 + (size_t)64*HID;
    u16* aL0 = &As[(wave*16)*32];
    u16* aL1 = &As[(64 + wave*16)*32];
    u16* bL0 = &Bs[(wave*16)*32];
    u16* bL1 = &Bs[(64 + wave*16)*32];

    for (int tile = mt0; tile < ntile; tile += CAP) {
        const int m0 = tile << 7;
        int nvalid = ne - m0; if (nvalid > 128) nvalid = 128;

        __syncthreads();
        if (tid < 128) {
            int i = (tid < nvalid) ? tid : (nvalid - 1);
            tLds[tid] = ctok[off + m0 + i];
            wLds[tid] = cwt [off + m0 + i];
        }
        __syncthreads();
        int ar0 = wave*16 + lrow;      if (ar0 >= nvalid) ar0 = nvalid - 1;
        int ar1 = 64 + wave*16 + lrow; if (ar1 >= nvalid) ar1 = nvalid - 1;
        const u16* ag0 = Hbuf + (size_t)(off + m0 + ar0)*HID + kb + lko;
        const u16* ag1 = Hbuf + (size_t)(off + m0 + ar1)*HID + kb + lko;

        f32x4 acc[4][4];
#pragma unroll
        for (int a = 0; a < 4; ++a)
#pragma unroll
            for (int b = 0; b < 4; ++b) acc[a][b] = (f32x4){0.f,0.f,0.f,0.f};

        for (int k0 = 0; k0 < HID/2; k0 += 32) {
            __syncthreads();
            glds16(ag0 + k0, aL0);
            glds16(ag1 + k0, aL1);
            glds16(bg0 + k0, bL0);
            glds16(bg1 + k0, bL1);
            __syncthreads();
            bf16x8 af[4], bf[4];
#pragma unroll
            for (int m = 0; m < 4; ++m)
                af[m] = *(const bf16x8*)&As[(wr*64 + m*16 + lr)*32 + quad*8];
#pragma unroll
            for (int n = 0; n < 4; ++n)
                bf[n] = *(const bf16x8*)&Bs[(wc*64 + n*16 + lr)*32 + quad*8];
#pragma unroll
            for (int m = 0; m < 4; ++m)
#pragma unroll
                for (int n = 0; n < 4; ++n)
                    acc[m][n] = __builtin_amdgcn_mfma_f32_16x16x32_bf16(af[m], bf[n], acc[m][n], 0, 0, 0);
        }

#pragma unroll
        for (int m = 0; m < 4; ++m) {
            int mb_ = wr*64 + m*16 + quad*4;
#pragma unroll
            for (int rr = 0; rr < 4; ++rr) {
                int mm = mb_ + rr;
                if (mm >= nvalid) continue;
                float wr_ = wLds[mm];
                float* orow = outf + (size_t)tLds[mm]*DIM + d0 + wc*64 + lr;
#pragma unroll
                for (int n = 0; n < 4; ++n)
                    atomicAdd(&orow[n*16], acc[m][n][rr] * wr_);
            }
        }
    }
}

extern "C" void kernel_launch(void* const* d_in, const int* in_sizes, int n_in,
                              void* d_out, int out_size, void* d_ws, size_t ws_size,
                              hipStream_t stream)
{
    const float* x  = (const float*)d_in[0];
    const float* wg = (const float*)d_in[1];
    const float* w1 = (const float*)d_in[2];
    const float* w2 = (const float*)d_in[3];
    const float* w3 = (const float*)d_in[4];
    float* outf = (float*)d_out;

    char* ws = (char*)d_ws;
    int*   cnt  = (int*)  (ws);                       //        256 B
    int*   tok  = (int*)  (ws + 256);                 //    131,072
    float* wt   = (float*)(ws + 131328);              //    131,072
    int*   ctok = (int*)  (ws + 262400);              //     32,768
    float* cwt  = (float*)(ws + 295168);              //     32,768
    u16*   Xbf  = (u16*)  (ws + 327936);              //  8,388,608
    u16*   Hbuf = (u16*)  (ws + 8716544);             // 46,137,344
    u16*   W1t  = (u16*)  (ws + 54853888);            // 46,137,344
    u16*   W3t  = (u16*)  (ws + 100991232);           // 46,137,344
    u16*   W2t  = (u16*)  (ws + 147128576);           // 46,137,344 -> 193,265,920 total

    hipMemsetAsync(cnt, 0, 256, stream);
    hipMemsetAsync(outf, 0, (size_t)T_TOK*DIM*sizeof(float), stream);

    k_transpose_cast<<<dim3(DIM/64, HID/64, NEXP), 256, 0, stream>>>(w1, W1t, DIM, HID);
    k_transpose_cast<<<dim3(DIM/64, HID/64, NEXP), 256, 0, stream>>>(w3, W3t, DIM, HID);
    k_transpose_cast<<<dim3(HID/64, DIM/64, NEXP), 256, 0, stream>>>(w2, W2t, HID, DIM);

    k_gating<<<T_TOK/4, 256, 0, stream>>>(x, wg, cnt, tok, wt, Xbf);
    k_compact<<<NEXP, 256, 0, stream>>>(cnt, tok, wt, ctok, cwt);

    k_gemm1<<<NEXP*(HID/64)*CAP, 256, 0, stream>>>(Xbf, W1t, W3t, Hbuf, cnt, ctok);
    k_gemm2<<<NEXP*CAP*2*(DIM/128), 256, 0, stream>>>(Hbuf, W2t, outf, cnt, ctok, cwt);
}